// Round 2
// baseline (269.019 us; speedup 1.0000x reference)
//
#include <hip/hip_runtime.h>
#include <stdint.h>

#define D_ 128
#define H_ 8
#define B_ 4
#define L_ 2048
#define NH (B_*H_)

typedef __bf16 bf16x8 __attribute__((ext_vector_type(8)));
typedef float f32x4 __attribute__((ext_vector_type(4)));
typedef unsigned short u16;
typedef u16 u16x8 __attribute__((ext_vector_type(8)));
typedef u16 u16x4 __attribute__((ext_vector_type(4)));
typedef float fvec4 __attribute__((ext_vector_type(4)));

__device__ __forceinline__ u16 f2b(float f){
    uint32_t u = __builtin_bit_cast(uint32_t, f);
    u += 0x7fffu + ((u >> 16) & 1u);
    return (u16)(u >> 16);
}
__device__ __forceinline__ bf16x8 asbf(u16x8 v){ return __builtin_bit_cast(bf16x8, v); }
#define MFMA(a,b,c) __builtin_amdgcn_mfma_f32_16x16x32_bf16((a),(b),(c),0,0,0)

// ---------------- kernel 0: convert x fp32 -> bf16 ----------------
__global__ __launch_bounds__(256)
void cvt_x(const float* __restrict__ x, u16* __restrict__ xb){
    size_t i = ((size_t)blockIdx.x*256 + threadIdx.x)*8;
    fvec4 lo = *(const fvec4*)&x[i];
    fvec4 hi = *(const fvec4*)&x[i+4];
    u16x8 u;
    for (int j=0;j<4;++j){ u[j]=f2b(lo[j]); u[4+j]=f2b(hi[j]); }
    *(u16x8*)&xb[i] = u;
}

// ---------------- kernel 1: QKV projection ----------------
// grid: (8 heads, 64 row-tiles of 128, 3 mats). block 256.
// Q: q_ws[bh][l][d] (pre-scaled by 1/sqrt(D)), K: k_ws[bh][l][d], V: v_ws[bh][d][l]
__global__ __launch_bounds__(256)
void qkv_proj(const u16* __restrict__ xb,
              const float* __restrict__ Wq, const float* __restrict__ Wk, const float* __restrict__ Wv,
              u16* __restrict__ q_ws, u16* __restrict__ k_ws, u16* __restrict__ v_ws)
{
    const int head = blockIdx.x;
    const int rt   = blockIdx.y;
    const int mat  = blockIdx.z;
    const float* W = (mat==0) ? Wq : ((mat==1) ? Wk : Wv);

    __shared__ u16 Ws[128][136];   // W^T tile: [n within head][k]

    const int t = threadIdx.x;
    const int row0 = rt*128;

    // stage W^T (fp32 -> bf16, transposed)
    for (int it=0; it<16; ++it){
        int k  = it*8 + (t>>5);
        int n0 = (t&31)*4;
        fvec4 wv = *(const fvec4*)&W[(size_t)k*(D_*H_) + head*128 + n0];
        for (int i=0;i<4;++i) Ws[n0+i][k] = f2b(wv[i]);
    }
    __syncthreads();

    const int wave = t>>6, lane = t&63;
    const int wr = wave>>1, wc = wave&1;
    const int lrow = lane&15, lk8 = (lane>>4)*8;

    f32x4 acc[4][4] = {};
    for (int kc=0;kc<4;++kc){
        bf16x8 a[4], b[4];
        for (int mr=0;mr<4;++mr)
            a[mr] = asbf(*(const u16x8*)&xb[(size_t)(row0+wr*64+mr*16+lrow)*D_ + kc*32 + lk8]);
        for (int nr=0;nr<4;++nr)
            b[nr] = asbf(*(const u16x8*)&Ws[wc*64+nr*16+lrow][kc*32 + lk8]);
        for (int mr=0;mr<4;++mr)
            for (int nr=0;nr<4;++nr)
                acc[mr][nr] = MFMA(a[mr], b[nr], acc[mr][nr]);
    }

    const float qscale = 0.08838834764831845f; // 1/sqrt(128)
    for (int mr=0;mr<4;++mr){
        for (int nr=0;nr<4;++nr){
            f32x4 v = acc[mr][nr];
            int baserow = row0 + wr*64 + mr*16 + (lane>>4)*4;   // 4 consecutive l
            int cd = wc*64 + nr*16 + lrow;                      // d within head
            int b  = baserow / L_;
            int l  = baserow % L_;    // row tiles never cross batch boundary (2048%128==0)
            int bh = b*H_ + head;
            if (mat==2){
                u16x4 pv;
                for (int r=0;r<4;++r) pv[r] = f2b(v[r]);
                *(u16x4*)&v_ws[((size_t)bh*D_ + cd)*L_ + l] = pv;
            } else {
                u16* dst = (mat==0) ? q_ws : k_ws;
                for (int r=0;r<4;++r){
                    float f = v[r];
                    if (mat==0) f *= qscale;
                    dst[((size_t)bh*L_ + (l + r))*D_ + cd] = f2b(f);
                }
            }
        }
    }
}

// ---------------- kernel 2: flash attention ----------------
// grid: (32 q-tiles, 32 bh). block 256 = 4 waves; wave handles 16 q rows.
__global__ __launch_bounds__(256)
void attn(const u16* __restrict__ q_ws, const u16* __restrict__ k_ws,
          const u16* __restrict__ v_ws, u16* __restrict__ o_ws)
{
    const int qt = blockIdx.x;
    const int bh = blockIdx.y;
    const int t = threadIdx.x, wave = t>>6, lane = t&63;
    const int lrow = lane&15, lgrp = lane>>4, lk8 = (lane>>4)*8;

    __shared__ u16 Ks[64][136];     // K tile row-major [kv][d]
    __shared__ u16 Vs[128][72];     // V^T tile [d][kv]
    __shared__ u16 Ps[4][16][72];   // per-wave P round-trip

    const int q0 = qt*64 + wave*16;
    bf16x8 qf[4];
    for (int kc=0;kc<4;++kc)
        qf[kc] = asbf(*(const u16x8*)&q_ws[((size_t)bh*L_ + q0 + lrow)*D_ + kc*32 + lk8]);

    float m[4], lsum[4];
    for (int r=0;r<4;++r){ m[r] = -1e30f; lsum[r] = 0.f; }
    f32x4 o[8] = {};

    for (int kt=0; kt<L_/64; ++kt){
        const int kv0 = kt*64;
        // stage K (64x128)
        for (int it=0; it<4; ++it){
            int r = it*16 + (t>>4), d0 = (t&15)*8;
            *(u16x8*)&Ks[r][d0] = *(const u16x8*)&k_ws[((size_t)bh*L_ + kv0 + r)*D_ + d0];
        }
        // stage V^T (128x64)
        for (int it=0; it<4; ++it){
            int d = it*32 + (t>>3), c0 = (t&7)*8;
            *(u16x8*)&Vs[d][c0] = *(const u16x8*)&v_ws[((size_t)bh*D_ + d)*L_ + kv0 + c0];
        }
        __syncthreads();

        // S = Q K^T (scale pre-folded into Q)
        f32x4 s[4];
        for (int nc=0;nc<4;++nc){
            f32x4 accs = {};
            for (int kc=0;kc<4;++kc){
                bf16x8 kb = asbf(*(const u16x8*)&Ks[nc*16+lrow][kc*32 + lk8]);
                accs = MFMA(qf[kc], kb, accs);
            }
            s[nc] = accs;
        }

        // online softmax
        float mx[4];
        for (int r=0;r<4;++r)
            mx[r] = fmaxf(fmaxf(s[0][r],s[1][r]), fmaxf(s[2][r],s[3][r]));
        for (int off=1; off<16; off<<=1)
            for (int r=0;r<4;++r) mx[r] = fmaxf(mx[r], __shfl_xor(mx[r], off, 64));
        float alpha[4], mn[4];
        for (int r=0;r<4;++r){
            mn[r] = fmaxf(m[r], mx[r]);
            alpha[r] = __expf(m[r] - mn[r]);
            m[r] = mn[r];
        }
        float rs[4] = {0.f,0.f,0.f,0.f};
        for (int nc=0;nc<4;++nc)
            for (int r=0;r<4;++r){
                float p = __expf(s[nc][r] - mn[r]);
                s[nc][r] = p;
                rs[r] += p;
            }
        for (int off=1; off<16; off<<=1)
            for (int r=0;r<4;++r) rs[r] += __shfl_xor(rs[r], off, 64);
        for (int r=0;r<4;++r) lsum[r] = lsum[r]*alpha[r] + rs[r];
        for (int dc=0;dc<8;++dc)
            for (int r=0;r<4;++r) o[dc][r] *= alpha[r];

        // P -> bf16 -> LDS (per-wave region)
        for (int nc=0;nc<4;++nc)
            for (int r=0;r<4;++r)
                Ps[wave][lgrp*4+r][nc*16+lrow] = f2b(s[nc][r]);
        asm volatile("s_waitcnt lgkmcnt(0)" ::: "memory");

        // O += P V
        for (int kc2=0;kc2<2;++kc2){
            bf16x8 pa = asbf(*(const u16x8*)&Ps[wave][lrow][kc2*32 + lk8]);
            for (int dc=0;dc<8;++dc){
                bf16x8 vb = asbf(*(const u16x8*)&Vs[dc*16+lrow][kc2*32 + lk8]);
                o[dc] = MFMA(pa, vb, o[dc]);
            }
        }
        __syncthreads();
    }

    // epilogue: normalize, store bf16 to o_ws[b][l][h*128+d]
    const int b = bh / H_, h = bh % H_;
    for (int r=0;r<4;++r){
        float inv = 1.0f / lsum[r];
        int l = q0 + lgrp*4 + r;
        for (int dc=0;dc<8;++dc)
            o_ws[((size_t)(b*L_ + l))*(D_*H_) + h*128 + dc*16 + lrow] = f2b(o[dc][r]*inv);
    }
}

// ---------------- kernel 3: output projection + bias ----------------
// grid: 128 blocks of 64 rows. block 256 = 4 waves; wave handles 16 rows x 128 cols.
__global__ __launch_bounds__(256)
void out_proj(const u16* __restrict__ o_ws, const float* __restrict__ Wu,
              const float* __restrict__ bu, float* __restrict__ out)
{
    const int rt = blockIdx.x;
    const int t = threadIdx.x, wave = t>>6, lane = t&63;
    const int lrow = lane&15, lgrp = lane>>4, lk8 = (lane>>4)*8;

    __shared__ u16 As[64][136];    // o_ws tile [row][k]
    __shared__ u16 Wt[128][136];   // Wu^T tile [n][k]

    const int row0 = rt*64;
    f32x4 acc[8] = {};

    for (int ks=0; ks<8; ++ks){
        for (int it=0; it<4; ++it){
            int r = it*16 + (t>>4), k0 = (t&15)*8;
            *(u16x8*)&As[r][k0] = *(const u16x8*)&o_ws[(size_t)(row0+r)*(D_*H_) + ks*128 + k0];
        }
        for (int it=0; it<16; ++it){
            int k  = it*8 + (t>>5);
            int n0 = (t&31)*4;
            fvec4 wv = *(const fvec4*)&Wu[(size_t)(ks*128 + k)*D_ + n0];
            for (int i=0;i<4;++i) Wt[n0+i][k] = f2b(wv[i]);
        }
        __syncthreads();

        for (int kc=0;kc<4;++kc){
            bf16x8 a = asbf(*(const u16x8*)&As[wave*16+lrow][kc*32 + lk8]);
            for (int nc=0;nc<8;++nc){
                bf16x8 b = asbf(*(const u16x8*)&Wt[nc*16+lrow][kc*32 + lk8]);
                acc[nc] = MFMA(a, b, acc[nc]);
            }
        }
        __syncthreads();
    }

    for (int nc=0;nc<8;++nc){
        for (int r=0;r<4;++r){
            int row = row0 + wave*16 + lgrp*4 + r;
            int n = nc*16 + lrow;
            out[(size_t)row*D_ + n] = acc[nc][r] + bu[n];
        }
    }
}

// ---------------- launcher ----------------
extern "C" void kernel_launch(void* const* d_in, const int* in_sizes, int n_in,
                              void* d_out, int out_size, void* d_ws, size_t ws_size,
                              hipStream_t stream)
{
    const float* x  = (const float*)d_in[0];
    const float* Wq = (const float*)d_in[1];
    const float* Wk = (const float*)d_in[2];
    const float* Wv = (const float*)d_in[3];
    const float* Wu = (const float*)d_in[4];
    const float* bu = (const float*)d_in[5];
    float* out = (float*)d_out;

    u16* ws = (u16*)d_ws;
    const size_t SZ = (size_t)NH * L_ * D_;   // 8,388,608 elements
    u16* q_ws = ws;
    u16* k_ws = q_ws + SZ;
    u16* v_ws = k_ws + SZ;
    u16* o_ws = v_ws + SZ;                    // [B*L][H*D] bf16, same element count
    u16* x_bf = o_ws + SZ;                    // 1,048,576 elements

    cvt_x<<<dim3((B_*L_*D_)/(256*8)), 256, 0, stream>>>(x, x_bf);
    qkv_proj<<<dim3(H_, (B_*L_)/128, 3), 256, 0, stream>>>(x_bf, Wq, Wk, Wv, q_ws, k_ws, v_ws);
    attn<<<dim3(L_/64, NH), 256, 0, stream>>>(q_ws, k_ws, v_ws, o_ws);
    out_proj<<<dim3((B_*L_)/64), 256, 0, stream>>>(o_ws, Wu, bu, out);
}